// Round 15
// baseline (174.698 us; speedup 1.0000x reference)
//
#include <hip/hip_runtime.h>

#define DIN 128
#define DOUT 128

typedef float f4 __attribute__((ext_vector_type(4)));
typedef float f32x4 __attribute__((ext_vector_type(4)));
typedef short bf16x8 __attribute__((ext_vector_type(8)));
typedef unsigned short u16x8 __attribute__((ext_vector_type(8)));
typedef unsigned short u16x4 __attribute__((ext_vector_type(4)));

__device__ inline unsigned short f2bf(float f) {
    unsigned u = __float_as_uint(f);
    u += 0x7FFFu + ((u >> 16) & 1u);   // round-to-nearest-even
    return (unsigned short)(u >> 16);
}

// Fused preamble: blocks [0,nbW) build Wt (bf16, transposed [m][dout][din]);
// [nbW, nbW+nbX) build xbf; rest do deg_count atomics. Independent work.
__global__ void preamble(const float* __restrict__ W, const float* __restrict__ Wl,
                         const float* __restrict__ x, const int* __restrict__ dst,
                         unsigned short* __restrict__ Wt, unsigned short* __restrict__ xbf,
                         int* __restrict__ cnt,
                         int nbW, int nbX, int E, int N, int totE) {
    const int b = blockIdx.x;
    const int t = threadIdx.x;
    if (b < nbW) {
        int id = b * 256 + t;
        if (id >= 5 * DIN * DOUT) return;
        int m    = id >> 14;
        int rem  = id & 16383;
        int din  = rem >> 7;
        int dout = rem & 127;
        float v = (m < 4) ? W[(m << 14) + din * DOUT + dout] : Wl[din * DOUT + dout];
        Wt[(m << 14) + dout * DIN + din] = f2bf(v);
    } else if (b < nbW + nbX) {
        int tid = (b - nbW) * 256 + t;
        if (tid >= N * 16) return;
        const float* xr = x + (long long)tid * 8;
        f4 lo = *(const f4*)xr;
        f4 hi = *(const f4*)(xr + 4);
        u16x8 p;
        p[0] = f2bf(lo[0]); p[1] = f2bf(lo[1]); p[2] = f2bf(lo[2]); p[3] = f2bf(lo[3]);
        p[4] = f2bf(hi[0]); p[5] = f2bf(hi[1]); p[6] = f2bf(hi[2]); p[7] = f2bf(hi[3]);
        *(u16x8*)&xbf[(long long)tid * 8] = p;
    } else {
        int i = (b - nbW - nbX) * 256 + t;
        if (i >= totE) return;
        int r = i / E;
        atomicAdd(&cnt[r * N + dst[i]], 1);
    }
}

// ---- 3-pass exclusive scan over M = R*N ints (2048 items / block) ----
__global__ void scan1(const int* __restrict__ cnt, int* __restrict__ off,
                      int* __restrict__ part, int M) {
    __shared__ int sd[256];
    const int t = threadIdx.x, b = blockIdx.x;
    const int base = b * 2048 + t * 8;
    int v[8]; int tsum = 0;
    #pragma unroll
    for (int i = 0; i < 8; i++) { int g = base + i; v[i] = (g < M) ? cnt[g] : 0; tsum += v[i]; }
    sd[t] = tsum; __syncthreads();
    for (int d = 1; d < 256; d <<= 1) {
        int val = 0;
        if (t >= d) val = sd[t - d];
        __syncthreads();
        if (t >= d) sd[t] += val;
        __syncthreads();
    }
    int run = sd[t] - tsum;
    if (t == 255) part[b] = sd[255];
    #pragma unroll
    for (int i = 0; i < 8; i++) { int g = base + i; if (g < M) off[g] = run; run += v[i]; }
}

// Single block; requires nb <= 256 (R*N=400k -> nb=196).
__global__ void scan2(int* __restrict__ part, int nb, int* __restrict__ offM) {
    __shared__ int sd[256];
    const int t = threadIdx.x;
    int v = (t < nb) ? part[t] : 0;
    sd[t] = v; __syncthreads();
    for (int d = 1; d < 256; d <<= 1) {
        int val = 0;
        if (t >= d) val = sd[t - d];
        __syncthreads();
        if (t >= d) sd[t] += val;
        __syncthreads();
    }
    if (t < nb) part[t] = sd[t] - v;
    if (t == 255) *offM = sd[255];
}

__global__ void scan3(int* __restrict__ off, const int* __restrict__ part, int M) {
    const int add = part[blockIdx.x];
    const int base = blockIdx.x * 2048 + threadIdx.x;
    #pragma unroll
    for (int i = 0; i < 8; i++) { int g = base + i * 256; if (g < M) off[g] += add; }
}

// Scatter src ids into CSR slots; decrements cnt back to 0 (used as cursor).
__global__ void fill_csr(const int* __restrict__ src, const int* __restrict__ dst,
                         const int* __restrict__ off, int* __restrict__ cnt,
                         int* __restrict__ csr, int E, int N, int total) {
    int i = blockIdx.x * 256 + threadIdx.x;
    if (i >= total) return;
    int r = i / E;
    int idx = r * N + dst[i];
    int pos = atomicAdd(&cnt[idx], -1) - 1;
    csr[off[idx] + pos] = src[i];
}

// bf16 gather: thread = (rel, node, 16B chunk). 16 lanes cover one node row
// (256 B coalesced per edge). Accumulate fp32, write normalized bf16 agg.
__global__ __launch_bounds__(256)
void gather_bf(const unsigned short* __restrict__ xbf, const int* __restrict__ off,
               const int* __restrict__ csr, unsigned short* __restrict__ agg,
               int N, int total) {
    int tid = blockIdx.x * 256 + threadIdx.x;
    if (tid >= total) return;
    const int c  = tid & 15;
    const int nn = tid >> 4;
    const int n  = nn % N;
    const int rr = nn / N;

    const int idx = rr * N + n;
    const int s0 = off[idx];
    const int s1 = off[idx + 1];

    float acc[8];
    #pragma unroll
    for (int i = 0; i < 8; i++) acc[i] = 0.0f;

    for (int e = s0; e < s1; e++) {
        const int s = csr[e];
        u16x8 v = *(const u16x8*)&xbf[(long long)s * DIN + c * 8];
        #pragma unroll
        for (int i = 0; i < 8; i++)
            acc[i] += __uint_as_float(((unsigned)v[i]) << 16);
    }
    const float sc = 1.0f / fmaxf((float)(s1 - s0), 1.0f);
    u16x8 p;
    #pragma unroll
    for (int i = 0; i < 8; i++) p[i] = f2bf(acc[i] * sc);
    *(u16x8*)&agg[((long long)rr * N + n) * DIN + c * 8] = p;
}

// fp32-x gather fallback (tiny ws): 32 lanes cover one node row.
__global__ __launch_bounds__(256)
void gather_f32(const float* __restrict__ x, const int* __restrict__ off,
                const int* __restrict__ csr, unsigned short* __restrict__ agg,
                int r0, int N, int total) {
    int tid = blockIdx.x * 256 + threadIdx.x;
    if (tid >= total) return;
    const int c  = tid & 31;
    const int nn = tid >> 5;
    const int n  = nn % N;
    const int rr = nn / N;

    const int idx = (r0 + rr) * N + n;
    const int s0 = off[idx];
    const int s1 = off[idx + 1];

    f4 acc = (f4)(0.0f);
    for (int e = s0; e < s1; e++) {
        const int s = csr[e];
        acc += *(const f4*)&x[(long long)s * DIN + c * 4];
    }
    const float sc = 1.0f / fmaxf((float)(s1 - s0), 1.0f);
    acc *= sc;

    u16x4 p;
    p[0] = f2bf(acc[0]); p[1] = f2bf(acc[1]);
    p[2] = f2bf(acc[2]); p[3] = f2bf(acc[3]);
    *(u16x4*)&agg[((long long)rr * N + n) * DIN + c * 4] = p;
}

// GEMM, 128-row tiles (8 waves): W staged per-relation into XOR-swizzled LDS
// (B-frag ds_read_b128 conflict-free), A-frags (all bf16: agg rels 0..3, xbf
// as rel 4) prefetched into regs one relation ahead. 2 barriers/relation.
__global__ __launch_bounds__(512, 2)
void gemm_lds(const unsigned short* __restrict__ agg,   // [4][N][128] bf16
              const unsigned short* __restrict__ xbf,   // [N][128] bf16
              const unsigned short* __restrict__ Wt,    // [5][128][128] bf16
              const float* __restrict__ bias,
              float* __restrict__ out, int N) {
    __shared__ unsigned short Ws[128 * 128];   // 32 KB, swizzled: slot ^= (row&7)

    const int t    = threadIdx.x;
    const int lane = t & 63;
    const int w    = t >> 6;          // 0..7
    const int n0   = blockIdx.x * 128;
    const int lr   = lane & 15;
    const int kg   = lane >> 4;
    const int lrm  = lr & 7;

    const int rowA = n0 + w * 16 + lr;
    const int rowC = (rowA < N) ? rowA : (N - 1);   // clamp tail (stores guarded)

    const long long relStride = (long long)N * DIN;

    f32x4 acc[8];
    #pragma unroll
    for (int ct = 0; ct < 8; ct++) acc[ct] = (f32x4)(0.0f);

    // A source per "relation" slot: rels 0..3 = agg, 4 = xbf (self-loop)
    const unsigned short* aSrc0 = agg + (long long)rowC * DIN;

    bf16x8 aCur[4], aNxt[4];
    #pragma unroll
    for (int k = 0; k < 4; k++)
        aCur[k] = *(const bf16x8*)&aSrc0[k * 32 + kg * 8];

    for (int r = 0; r < 5; r++) {
        // stage W_r -> LDS (swizzled): 2048 x 16B pieces, 4 per thread
        {
            const unsigned short* Wg = Wt + ((long long)r << 14);
            u16x8 tmp[4];
            #pragma unroll
            for (int p = 0; p < 4; p++) {
                const int li = t + p * 512;
                tmp[p] = *(const u16x8*)&Wg[((li >> 4) << 7) + (li & 15) * 8];
            }
            #pragma unroll
            for (int p = 0; p < 4; p++) {
                const int li  = t + p * 512;
                const int row = li >> 4, cg = li & 15;
                *(u16x8*)&Ws[(row << 7) + ((cg ^ (row & 7)) << 3)] = tmp[p];
            }
        }
        // prefetch next slot's A-frags (rel r+1, or xbf for slot 4)
        if (r < 4) {
            const unsigned short* an = (r < 3)
                ? agg + (r + 1) * relStride + (long long)rowC * DIN
                : xbf + (long long)rowC * DIN;
            #pragma unroll
            for (int k = 0; k < 4; k++)
                aNxt[k] = *(const bf16x8*)&an[k * 32 + kg * 8];
        }
        __syncthreads();   // W_r staged

        #pragma unroll
        for (int k0i = 0; k0i < 4; k0i++) {
            #pragma unroll
            for (int ct = 0; ct < 8; ct++) {
                const int row  = ct * 16 + lr;
                const int slot = (k0i * 4 + kg) ^ lrm;
                bf16x8 b = *(const bf16x8*)&Ws[(row << 7) + (slot << 3)];
                acc[ct] = __builtin_amdgcn_mfma_f32_16x16x32_bf16(aCur[k0i], b, acc[ct], 0, 0, 0);
            }
        }
        if (r < 4) {
            #pragma unroll
            for (int k = 0; k < 4; k++) aCur[k] = aNxt[k];
            __syncthreads();   // all waves done reading Ws before restage
        }
    }

    // epilogue: D[m][n] -> n = lane&15 (dout), m = kg*4 + j (node row)
    #pragma unroll
    for (int j = 0; j < 4; j++) {
        int n2 = n0 + w * 16 + kg * 4 + j;
        if (n2 >= N) continue;
        float* orow = out + (long long)n2 * DOUT + lr;
        #pragma unroll
        for (int ct = 0; ct < 8; ct++) {
            float v = acc[ct][j] + bias[ct * 16 + lr];
            orow[ct * 16] = fmaxf(v, 0.0f);
        }
    }
}

// Tiny-ws fallback: zero-LDS direct GEMM, per-relation accumulate.
__global__ __launch_bounds__(256, 4)
void gemm_direct(const float* __restrict__ x, const unsigned short* __restrict__ agg,
                 const unsigned short* __restrict__ Wt, const float* __restrict__ bias,
                 float* __restrict__ out, int N, int relStart, int nRel,
                 int doSelf, int accumulate) {
    const int t    = threadIdx.x;
    const int lane = t & 63;
    const int w    = t >> 6;
    const int n0   = blockIdx.x * 64;
    const int lr   = lane & 15;
    const int kg   = lane >> 4;

    const int rowA = n0 + w * 16 + lr;
    const int rowC = (rowA < N) ? rowA : (N - 1);

    f32x4 acc[8];
    #pragma unroll
    for (int ct = 0; ct < 8; ct++) acc[ct] = (f32x4)(0.0f);

    for (int rr = 0; rr < nRel; rr++) {
        const unsigned short* aggR = agg + ((long long)rr * N + rowC) * DIN;
        const unsigned short* WtR  = Wt + ((long long)(relStart + rr) << 14);
        #pragma unroll
        for (int k0 = 0; k0 < DIN; k0 += 32) {
            bf16x8 a = *(const bf16x8*)&aggR[k0 + kg * 8];
            #pragma unroll
            for (int ct = 0; ct < 8; ct++) {
                bf16x8 bfr = *(const bf16x8*)&WtR[((ct * 16 + lr) << 7) + k0 + kg * 8];
                acc[ct] = __builtin_amdgcn_mfma_f32_16x16x32_bf16(a, bfr, acc[ct], 0, 0, 0);
            }
        }
    }

    if (doSelf) {
        const float* xr = x + (long long)rowC * DIN;
        const unsigned short* WtS = Wt + ((long long)4 << 14);
        #pragma unroll
        for (int k0 = 0; k0 < DIN; k0 += 32) {
            f4 v  = *(const f4*)(xr + k0 + kg * 8);
            f4 v2 = *(const f4*)(xr + k0 + kg * 8 + 4);
            bf16x8 a;
            a[0] = (short)f2bf(v[0]);  a[1] = (short)f2bf(v[1]);
            a[2] = (short)f2bf(v[2]);  a[3] = (short)f2bf(v[3]);
            a[4] = (short)f2bf(v2[0]); a[5] = (short)f2bf(v2[1]);
            a[6] = (short)f2bf(v2[2]); a[7] = (short)f2bf(v2[3]);
            #pragma unroll
            for (int ct = 0; ct < 8; ct++) {
                bf16x8 bfr = *(const bf16x8*)&WtS[((ct * 16 + lr) << 7) + k0 + kg * 8];
                acc[ct] = __builtin_amdgcn_mfma_f32_16x16x32_bf16(a, bfr, acc[ct], 0, 0, 0);
            }
        }
    }

    #pragma unroll
    for (int j = 0; j < 4; j++) {
        int n2 = n0 + w * 16 + kg * 4 + j;
        if (n2 >= N) continue;
        float* orow = out + (long long)n2 * DOUT + lr;
        #pragma unroll
        for (int ct = 0; ct < 8; ct++) {
            float v = acc[ct][j];
            if (accumulate) v += orow[ct * 16];
            if (doSelf) {
                v += bias[ct * 16 + lr];
                v = fmaxf(v, 0.0f);
            }
            orow[ct * 16] = v;
        }
    }
}

extern "C" void kernel_launch(void* const* d_in, const int* in_sizes, int n_in,
                              void* d_out, int out_size, void* d_ws, size_t ws_size,
                              hipStream_t stream) {
    const float* x  = (const float*)d_in[0];
    const float* W  = (const float*)d_in[1];
    const float* Wl = (const float*)d_in[2];
    const float* b  = (const float*)d_in[3];
    const int* src  = (const int*)d_in[4];
    const int* dst  = (const int*)d_in[5];
    float* out = (float*)d_out;

    const int N = in_sizes[0] / DIN;
    const int R = in_sizes[1] / (DIN * DOUT);
    const int E = in_sizes[4] / R;
    const int M = R * N;
    const int totE = R * E;

    // workspace layout
    char* wsp = (char*)d_ws;
    unsigned short* Wt = (unsigned short*)wsp;          // 5*16384 bf16 = 160 KB
    int* cnt  = (int*)(wsp + 5 * 16384 * 2);            // [M]
    int* off  = cnt + M;                                // [M+1]
    int* part = off + M + 1;                            // [256]
    int* csr  = part + 256;                             // [totE]
    size_t preBytes = ((char*)(csr + totE) - wsp + 255) & ~(size_t)255;
    unsigned short* agg = (unsigned short*)(wsp + preBytes);   // [4][N][128] + xbf
    const size_t aggBytes = (size_t)N * DIN * sizeof(unsigned short);
    const bool pathA = (ws_size >= preBytes + 5 * aggBytes) && (R == 4);

    hipMemsetAsync(cnt, 0, (size_t)M * sizeof(int), stream);

    const int nb = (M + 2047) / 2048;

    if (pathA) {
        unsigned short* xbf = agg + 4 * (size_t)N * DIN;

        const int nbW = (5 * DIN * DOUT + 255) / 256;
        const int nbX = (N * 16 + 255) / 256;
        const int nbD = (totE + 255) / 256;
        preamble<<<nbW + nbX + nbD, 256, 0, stream>>>(W, Wl, x, dst, Wt, xbf, cnt,
                                                      nbW, nbX, E, N, totE);

        scan1<<<nb, 256, 0, stream>>>(cnt, off, part, M);
        scan2<<<1, 256, 0, stream>>>(part, nb, off + M);
        scan3<<<nb, 256, 0, stream>>>(off, part, M);
        fill_csr<<<(totE + 255) / 256, 256, 0, stream>>>(src, dst, off, cnt, csr, E, N, totE);

        const int total = R * N * 16;
        gather_bf<<<(total + 255) / 256, 256, 0, stream>>>(xbf, off, csr, agg, N, total);

        gemm_lds<<<(N + 127) / 128, 512, 0, stream>>>(agg, xbf, Wt, b, out, N);
    } else {
        // tiny-ws fallback: per-relation gather + direct GEMM (1 agg slot)
        const int nbW = (5 * DIN * DOUT + 255) / 256;
        const int nbD = (totE + 255) / 256;
        preamble<<<nbW + nbD, 256, 0, stream>>>(W, Wl, x, dst, Wt, nullptr, cnt,
                                                nbW, 0, E, N, totE);
        scan1<<<nb, 256, 0, stream>>>(cnt, off, part, M);
        scan2<<<1, 256, 0, stream>>>(part, nb, off + M);
        scan3<<<nb, 256, 0, stream>>>(off, part, M);
        fill_csr<<<(totE + 255) / 256, 256, 0, stream>>>(src, dst, off, cnt, csr, E, N, totE);

        const int total = N * 32;
        const int gemmGrid = (N + 63) / 64;
        for (int r = 0; r < R; r++) {
            gather_f32<<<(total + 255) / 256, 256, 0, stream>>>(x, off, csr, agg, r, N, total);
            gemm_direct<<<gemmGrid, 256, 0, stream>>>(x, agg, Wt, b, out, N,
                                                      r, 1, /*doSelf=*/(r == R - 1),
                                                      /*accumulate=*/(r > 0));
        }
    }
}

// Round 16
// 168.499 us; speedup vs baseline: 1.0368x; 1.0368x over previous
//
#include <hip/hip_runtime.h>

#define DIN 128
#define DOUT 128

typedef float f4 __attribute__((ext_vector_type(4)));
typedef float f32x4 __attribute__((ext_vector_type(4)));
typedef short bf16x8 __attribute__((ext_vector_type(8)));
typedef unsigned short u16x8 __attribute__((ext_vector_type(8)));
typedef unsigned short u16x4 __attribute__((ext_vector_type(4)));

__device__ inline unsigned short f2bf(float f) {
    unsigned u = __float_as_uint(f);
    u += 0x7FFFu + ((u >> 16) & 1u);   // round-to-nearest-even
    return (unsigned short)(u >> 16);
}

// Fused preamble: blocks [0,nbW) build Wt (bf16, transposed [m][dout][din]);
// [nbW, nbW+nbX) build xbf; rest do deg_count atomics. Independent work.
__global__ void preamble(const float* __restrict__ W, const float* __restrict__ Wl,
                         const float* __restrict__ x, const int* __restrict__ dst,
                         unsigned short* __restrict__ Wt, unsigned short* __restrict__ xbf,
                         int* __restrict__ cnt,
                         int nbW, int nbX, int E, int N, int totE) {
    const int b = blockIdx.x;
    const int t = threadIdx.x;
    if (b < nbW) {
        int id = b * 256 + t;
        if (id >= 5 * DIN * DOUT) return;
        int m    = id >> 14;
        int rem  = id & 16383;
        int din  = rem >> 7;
        int dout = rem & 127;
        float v = (m < 4) ? W[(m << 14) + din * DOUT + dout] : Wl[din * DOUT + dout];
        Wt[(m << 14) + dout * DIN + din] = f2bf(v);
    } else if (b < nbW + nbX) {
        int tid = (b - nbW) * 256 + t;
        if (tid >= N * 16) return;
        const float* xr = x + (long long)tid * 8;
        f4 lo = *(const f4*)xr;
        f4 hi = *(const f4*)(xr + 4);
        u16x8 p;
        p[0] = f2bf(lo[0]); p[1] = f2bf(lo[1]); p[2] = f2bf(lo[2]); p[3] = f2bf(lo[3]);
        p[4] = f2bf(hi[0]); p[5] = f2bf(hi[1]); p[6] = f2bf(hi[2]); p[7] = f2bf(hi[3]);
        *(u16x8*)&xbf[(long long)tid * 8] = p;
    } else {
        int i = (b - nbW - nbX) * 256 + t;
        if (i >= totE) return;
        int r = i / E;
        atomicAdd(&cnt[r * N + dst[i]], 1);
    }
}

// scan1: per-block (2048 items) exclusive scan -> off (block-LOCAL), part[b]=block sum.
__global__ void scan1(const int* __restrict__ cnt, int* __restrict__ off,
                      int* __restrict__ part, int M) {
    __shared__ int sd[256];
    const int t = threadIdx.x, b = blockIdx.x;
    const int base = b * 2048 + t * 8;
    int v[8]; int tsum = 0;
    #pragma unroll
    for (int i = 0; i < 8; i++) { int g = base + i; v[i] = (g < M) ? cnt[g] : 0; tsum += v[i]; }
    sd[t] = tsum; __syncthreads();
    for (int d = 1; d < 256; d <<= 1) {
        int val = 0;
        if (t >= d) val = sd[t - d];
        __syncthreads();
        if (t >= d) sd[t] += val;
        __syncthreads();
    }
    int run = sd[t] - tsum;
    if (t == 255) part[b] = sd[255];
    #pragma unroll
    for (int i = 0; i < 8; i++) { int g = base + i; if (g < M) off[g] = run; run += v[i]; }
}

// scan2 (single block): part[b] -> absolute exclusive prefix in place; part[nb] = total.
// Consumers compose off_abs(idx) = off[idx] + part[idx>>11].
__global__ void scan2(int* __restrict__ part, int nb) {
    __shared__ int sd[256];
    const int t = threadIdx.x;
    int v = (t < nb) ? part[t] : 0;
    sd[t] = v; __syncthreads();
    for (int d = 1; d < 256; d <<= 1) {
        int val = 0;
        if (t >= d) val = sd[t - d];
        __syncthreads();
        if (t >= d) sd[t] += val;
        __syncthreads();
    }
    if (t < nb) part[t] = sd[t] - v;
    if (t == 255) part[nb] = sd[255];
}

// Scatter src ids into CSR slots; decrements cnt back to 0 (used as cursor).
__global__ void fill_csr(const int* __restrict__ src, const int* __restrict__ dst,
                         const int* __restrict__ off, const int* __restrict__ part,
                         int* __restrict__ cnt, int* __restrict__ csr,
                         int E, int N, int total) {
    int i = blockIdx.x * 256 + threadIdx.x;
    if (i >= total) return;
    int r = i / E;
    int idx = r * N + dst[i];
    int pos = atomicAdd(&cnt[idx], -1) - 1;
    csr[off[idx] + part[idx >> 11] + pos] = src[i];
}

// bf16 gather: thread = (rel, node, 16B chunk). 16 lanes cover one node row
// (256 B coalesced per edge). Accumulate fp32, write normalized bf16 agg.
__global__ __launch_bounds__(256)
void gather_bf(const unsigned short* __restrict__ xbf, const int* __restrict__ off,
               const int* __restrict__ part, const int* __restrict__ csr,
               unsigned short* __restrict__ agg, int N, int M, int total) {
    int tid = blockIdx.x * 256 + threadIdx.x;
    if (tid >= total) return;
    const int c  = tid & 15;
    const int nn = tid >> 4;
    const int n  = nn % N;
    const int rr = nn / N;

    const int idx = rr * N + n;
    const int s0 = off[idx] + part[idx >> 11];
    const int i1 = idx + 1;
    const int s1 = (i1 < M) ? (off[i1] + part[i1 >> 11]) : part[(M + 2047) >> 11];

    float acc[8];
    #pragma unroll
    for (int i = 0; i < 8; i++) acc[i] = 0.0f;

    for (int e = s0; e < s1; e++) {
        const int s = csr[e];
        u16x8 v = *(const u16x8*)&xbf[(long long)s * DIN + c * 8];
        #pragma unroll
        for (int i = 0; i < 8; i++)
            acc[i] += __uint_as_float(((unsigned)v[i]) << 16);
    }
    const float sc = 1.0f / fmaxf((float)(s1 - s0), 1.0f);
    u16x8 p;
    #pragma unroll
    for (int i = 0; i < 8; i++) p[i] = f2bf(acc[i] * sc);
    *(u16x8*)&agg[((long long)rr * N + n) * DIN + c * 8] = p;
}

// fp32-x gather fallback (tiny ws): 32 lanes cover one node row.
__global__ __launch_bounds__(256)
void gather_f32(const float* __restrict__ x, const int* __restrict__ off,
                const int* __restrict__ part, const int* __restrict__ csr,
                unsigned short* __restrict__ agg, int r0, int N, int M, int total) {
    int tid = blockIdx.x * 256 + threadIdx.x;
    if (tid >= total) return;
    const int c  = tid & 31;
    const int nn = tid >> 5;
    const int n  = nn % N;
    const int rr = nn / N;

    const int idx = (r0 + rr) * N + n;
    const int s0 = off[idx] + part[idx >> 11];
    const int i1 = idx + 1;
    const int s1 = (i1 < M) ? (off[i1] + part[i1 >> 11]) : part[(M + 2047) >> 11];

    f4 acc = (f4)(0.0f);
    for (int e = s0; e < s1; e++) {
        const int s = csr[e];
        acc += *(const f4*)&x[(long long)s * DIN + c * 4];
    }
    const float sc = 1.0f / fmaxf((float)(s1 - s0), 1.0f);
    acc *= sc;

    u16x4 p;
    p[0] = f2bf(acc[0]); p[1] = f2bf(acc[1]);
    p[2] = f2bf(acc[2]); p[3] = f2bf(acc[3]);
    *(u16x4*)&agg[((long long)rr * N + n) * DIN + c * 4] = p;
}

// GEMM, 128-row tiles (8 waves), DOUBLE-BUFFERED W staging: issue W_{r+1}
// global loads + A-prefetch before MFMA(r), ds_write to other 32 KB buffer
// after, one barrier per relation. B-frag ds_read_b128 XOR-swizzle-free.
__global__ __launch_bounds__(512, 2)
void gemm_lds(const unsigned short* __restrict__ agg,   // [4][N][128] bf16
              const unsigned short* __restrict__ xbf,   // [N][128] bf16
              const unsigned short* __restrict__ Wt,    // [5][128][128] bf16
              const float* __restrict__ bias,
              float* __restrict__ out, int N) {
    __shared__ unsigned short Ws[2][128 * 128];   // 2 x 32 KB ping-pong

    const int t    = threadIdx.x;
    const int lane = t & 63;
    const int w    = t >> 6;          // 0..7
    const int n0   = blockIdx.x * 128;
    const int lr   = lane & 15;
    const int kg   = lane >> 4;
    const int lrm  = lr & 7;

    const int rowA = n0 + w * 16 + lr;
    const int rowC = (rowA < N) ? rowA : (N - 1);   // clamp tail (stores guarded)
    const long long relStride = (long long)N * DIN;

    f32x4 acc[8];
    #pragma unroll
    for (int ct = 0; ct < 8; ct++) acc[ct] = (f32x4)(0.0f);

    // this thread's 4 staging pieces (16 B each)
    int sRow[4], sCg[4];
    #pragma unroll
    for (int p = 0; p < 4; p++) { const int li = t + p * 512; sRow[p] = li >> 4; sCg[p] = li & 15; }

    // stage W0 + load A-frags rel0
    u16x8 tmp[4];
    #pragma unroll
    for (int p = 0; p < 4; p++)
        tmp[p] = *(const u16x8*)&Wt[(sRow[p] << 7) + sCg[p] * 8];

    bf16x8 aCur[4], aNxt[4];
    {
        const unsigned short* a0 = agg + (long long)rowC * DIN;
        #pragma unroll
        for (int k = 0; k < 4; k++)
            aCur[k] = *(const bf16x8*)&a0[k * 32 + kg * 8];
    }
    #pragma unroll
    for (int p = 0; p < 4; p++)
        *(u16x8*)&Ws[0][(sRow[p] << 7) + ((sCg[p] ^ (sRow[p] & 7)) << 3)] = tmp[p];
    __syncthreads();

    for (int r = 0; r < 5; r++) {
        // issue next relation's global loads BEFORE the MFMA cluster
        if (r < 4) {
            const unsigned short* Wg = Wt + ((long long)(r + 1) << 14);
            #pragma unroll
            for (int p = 0; p < 4; p++)
                tmp[p] = *(const u16x8*)&Wg[(sRow[p] << 7) + sCg[p] * 8];
            const unsigned short* an = (r < 3)
                ? agg + (r + 1) * relStride + (long long)rowC * DIN
                : xbf + (long long)rowC * DIN;
            #pragma unroll
            for (int k = 0; k < 4; k++)
                aNxt[k] = *(const bf16x8*)&an[k * 32 + kg * 8];
        }

        const unsigned short* Wb = Ws[r & 1];
        #pragma unroll
        for (int k0i = 0; k0i < 4; k0i++) {
            #pragma unroll
            for (int ct = 0; ct < 8; ct++) {
                const int row  = ct * 16 + lr;
                const int slot = (k0i * 4 + kg) ^ lrm;
                bf16x8 b = *(const bf16x8*)&Wb[(row << 7) + (slot << 3)];
                acc[ct] = __builtin_amdgcn_mfma_f32_16x16x32_bf16(aCur[k0i], b, acc[ct], 0, 0, 0);
            }
        }

        if (r < 4) {
            #pragma unroll
            for (int p = 0; p < 4; p++)
                *(u16x8*)&Ws[(r + 1) & 1][(sRow[p] << 7) + ((sCg[p] ^ (sRow[p] & 7)) << 3)] = tmp[p];
            #pragma unroll
            for (int k = 0; k < 4; k++) aCur[k] = aNxt[k];
            __syncthreads();
        }
    }

    // epilogue: D[m][n] -> n = lane&15 (dout), m = kg*4 + j (node row)
    #pragma unroll
    for (int j = 0; j < 4; j++) {
        int n2 = n0 + w * 16 + kg * 4 + j;
        if (n2 >= N) continue;
        float* orow = out + (long long)n2 * DOUT + lr;
        #pragma unroll
        for (int ct = 0; ct < 8; ct++) {
            float v = acc[ct][j] + bias[ct * 16 + lr];
            orow[ct * 16] = fmaxf(v, 0.0f);
        }
    }
}

// Tiny-ws fallback: zero-LDS direct GEMM, per-relation accumulate.
__global__ __launch_bounds__(256, 4)
void gemm_direct(const float* __restrict__ x, const unsigned short* __restrict__ agg,
                 const unsigned short* __restrict__ Wt, const float* __restrict__ bias,
                 float* __restrict__ out, int N, int relStart, int nRel,
                 int doSelf, int accumulate) {
    const int t    = threadIdx.x;
    const int lane = t & 63;
    const int w    = t >> 6;
    const int n0   = blockIdx.x * 64;
    const int lr   = lane & 15;
    const int kg   = lane >> 4;

    const int rowA = n0 + w * 16 + lr;
    const int rowC = (rowA < N) ? rowA : (N - 1);

    f32x4 acc[8];
    #pragma unroll
    for (int ct = 0; ct < 8; ct++) acc[ct] = (f32x4)(0.0f);

    for (int rr = 0; rr < nRel; rr++) {
        const unsigned short* aggR = agg + ((long long)rr * N + rowC) * DIN;
        const unsigned short* WtR  = Wt + ((long long)(relStart + rr) << 14);
        #pragma unroll
        for (int k0 = 0; k0 < DIN; k0 += 32) {
            bf16x8 a = *(const bf16x8*)&aggR[k0 + kg * 8];
            #pragma unroll
            for (int ct = 0; ct < 8; ct++) {
                bf16x8 bfr = *(const bf16x8*)&WtR[((ct * 16 + lr) << 7) + k0 + kg * 8];
                acc[ct] = __builtin_amdgcn_mfma_f32_16x16x32_bf16(a, bfr, acc[ct], 0, 0, 0);
            }
        }
    }

    if (doSelf) {
        const float* xr = x + (long long)rowC * DIN;
        const unsigned short* WtS = Wt + ((long long)4 << 14);
        #pragma unroll
        for (int k0 = 0; k0 < DIN; k0 += 32) {
            f4 v  = *(const f4*)(xr + k0 + kg * 8);
            f4 v2 = *(const f4*)(xr + k0 + kg * 8 + 4);
            bf16x8 a;
            a[0] = (short)f2bf(v[0]);  a[1] = (short)f2bf(v[1]);
            a[2] = (short)f2bf(v[2]);  a[3] = (short)f2bf(v[3]);
            a[4] = (short)f2bf(v2[0]); a[5] = (short)f2bf(v2[1]);
            a[6] = (short)f2bf(v2[2]); a[7] = (short)f2bf(v2[3]);
            #pragma unroll
            for (int ct = 0; ct < 8; ct++) {
                bf16x8 bfr = *(const bf16x8*)&WtS[((ct * 16 + lr) << 7) + k0 + kg * 8];
                acc[ct] = __builtin_amdgcn_mfma_f32_16x16x32_bf16(a, bfr, acc[ct], 0, 0, 0);
            }
        }
    }

    #pragma unroll
    for (int j = 0; j < 4; j++) {
        int n2 = n0 + w * 16 + kg * 4 + j;
        if (n2 >= N) continue;
        float* orow = out + (long long)n2 * DOUT + lr;
        #pragma unroll
        for (int ct = 0; ct < 8; ct++) {
            float v = acc[ct][j];
            if (accumulate) v += orow[ct * 16];
            if (doSelf) {
                v += bias[ct * 16 + lr];
                v = fmaxf(v, 0.0f);
            }
            orow[ct * 16] = v;
        }
    }
}

extern "C" void kernel_launch(void* const* d_in, const int* in_sizes, int n_in,
                              void* d_out, int out_size, void* d_ws, size_t ws_size,
                              hipStream_t stream) {
    const float* x  = (const float*)d_in[0];
    const float* W  = (const float*)d_in[1];
    const float* Wl = (const float*)d_in[2];
    const float* b  = (const float*)d_in[3];
    const int* src  = (const int*)d_in[4];
    const int* dst  = (const int*)d_in[5];
    float* out = (float*)d_out;

    const int N = in_sizes[0] / DIN;
    const int R = in_sizes[1] / (DIN * DOUT);
    const int E = in_sizes[4] / R;
    const int M = R * N;
    const int totE = R * E;

    // workspace layout
    char* wsp = (char*)d_ws;
    unsigned short* Wt = (unsigned short*)wsp;          // 5*16384 bf16 = 160 KB
    int* cnt  = (int*)(wsp + 5 * 16384 * 2);            // [M]
    int* off  = cnt + M;                                // [M] block-local exclusive
    int* part = off + M + 1;                            // [260] absolute block prefix
    int* csr  = part + 260;                             // [totE]
    size_t preBytes = ((char*)(csr + totE) - wsp + 255) & ~(size_t)255;
    unsigned short* agg = (unsigned short*)(wsp + preBytes);   // [4][N][128] + xbf
    const size_t aggBytes = (size_t)N * DIN * sizeof(unsigned short);
    const bool pathA = (ws_size >= preBytes + 5 * aggBytes) && (R == 4);

    hipMemsetAsync(cnt, 0, (size_t)M * sizeof(int), stream);

    const int nb = (M + 2047) / 2048;   // <= 256 required (400k -> 196)

    if (pathA) {
        unsigned short* xbf = agg + 4 * (size_t)N * DIN;

        const int nbW = (5 * DIN * DOUT + 255) / 256;
        const int nbX = (N * 16 + 255) / 256;
        const int nbD = (totE + 255) / 256;
        preamble<<<nbW + nbX + nbD, 256, 0, stream>>>(W, Wl, x, dst, Wt, xbf, cnt,
                                                      nbW, nbX, E, N, totE);

        scan1<<<nb, 256, 0, stream>>>(cnt, off, part, M);
        scan2<<<1, 256, 0, stream>>>(part, nb);
        fill_csr<<<(totE + 255) / 256, 256, 0, stream>>>(src, dst, off, part, cnt, csr,
                                                         E, N, totE);

        const int total = R * N * 16;
        gather_bf<<<(total + 255) / 256, 256, 0, stream>>>(xbf, off, part, csr, agg,
                                                           N, M, total);

        gemm_lds<<<(N + 127) / 128, 512, 0, stream>>>(agg, xbf, Wt, b, out, N);
    } else {
        // tiny-ws fallback: per-relation gather + direct GEMM (1 agg slot)
        const int nbW = (5 * DIN * DOUT + 255) / 256;
        const int nbD = (totE + 255) / 256;
        preamble<<<nbW + nbD, 256, 0, stream>>>(W, Wl, x, dst, Wt, nullptr, cnt,
                                                nbW, 0, E, N, totE);
        scan1<<<nb, 256, 0, stream>>>(cnt, off, part, M);
        scan2<<<1, 256, 0, stream>>>(part, nb);
        fill_csr<<<(totE + 255) / 256, 256, 0, stream>>>(src, dst, off, part, cnt, csr,
                                                         E, N, totE);

        const int total = N * 32;
        const int gemmGrid = (N + 63) / 64;
        for (int r = 0; r < R; r++) {
            gather_f32<<<(total + 255) / 256, 256, 0, stream>>>(x, off, part, csr, agg,
                                                                r, N, M, total);
            gemm_direct<<<gemmGrid, 256, 0, stream>>>(x, agg, Wt, b, out, N,
                                                      r, 1, /*doSelf=*/(r == R - 1),
                                                      /*accumulate=*/(r > 0));
        }
    }
}